// Round 2
// baseline (480.215 us; speedup 1.0000x reference)
//
#include <hip/hip_runtime.h>
#include <hip/hip_bf16.h>

#define TT 1024
#define DM 256
#define BCN 32

typedef __attribute__((ext_vector_type(8))) short short8;
typedef __attribute__((ext_vector_type(4))) float f32x4;

// ---------------------------------------------------------------------------
// Kernel 1: QKV projection.
// qkv[t][e] = sum_d x[d][t] * w_qkv[e][d] + b_qkv[e]
// Q,K stored (bc, t, d) bf16 (k-contiguous for score MFMA operands).
// V blocks compute V^T directly: Vt[e][t] = sum_d w_v[e][d] * x[d][t]
// grid (12 etiles, 16 ttiles, 32 bc), 256 threads.
// ---------------------------------------------------------------------------
__global__ __launch_bounds__(256) void qkv_kernel(
    const float* __restrict__ x, const float* __restrict__ w_qkv,
    const float* __restrict__ b_qkv,
    __hip_bfloat16* __restrict__ Qb, __hip_bfloat16* __restrict__ Kb,
    __hip_bfloat16* __restrict__ Vtb)
{
  const int et = blockIdx.x;   // 0..11 (0-3 Q, 4-7 K, 8-11 V)
  const int tt = blockIdx.y;   // 0..15
  const int bc = blockIdx.z;   // 0..31
  const int t0 = tt * 64;
  const int e0 = et * 64;      // row offset into w_qkv (768 rows)
  const bool vmode = (et >= 8);

  __shared__ __attribute__((aligned(16))) __hip_bfloat16 Xs[64][264]; // [t][d]
  __shared__ __attribute__((aligned(16))) __hip_bfloat16 Ws[64][264]; // [e][d]

  const int tid = threadIdx.x;
  const float* xbc = x + (size_t)bc * DM * TT;

  // stage x^T tile: Xs[t_local][d] = x[d][t0+t_local]  (coalesced global reads)
  {
    const int tx = tid & 63, db = tid >> 6;
    for (int i = 0; i < 64; ++i) {
      const int d = i * 4 + db;
      Xs[tx][d] = __float2bfloat16(xbc[(size_t)d * TT + t0 + tx]);
    }
  }
  // stage w tile rows e0..e0+63
  {
    const float4* wv = (const float4*)(w_qkv + (size_t)e0 * DM);
    for (int i = 0; i < 16; ++i) {
      const int idx = tid + i * 256;
      const int row = idx >> 6, c4 = idx & 63;
      float4 f = wv[row * 64 + c4];
      Ws[row][c4 * 4 + 0] = __float2bfloat16(f.x);
      Ws[row][c4 * 4 + 1] = __float2bfloat16(f.y);
      Ws[row][c4 * 4 + 2] = __float2bfloat16(f.z);
      Ws[row][c4 * 4 + 3] = __float2bfloat16(f.w);
    }
  }
  __syncthreads();

  const int w = tid >> 6, l = tid & 63, quad = l >> 4, lm = l & 15;
  f32x4 acc[4] = {};

  const __hip_bfloat16 (*Ap)[264] = vmode ? Ws : Xs;
  const __hip_bfloat16 (*Bp)[264] = vmode ? Xs : Ws;
  for (int ks = 0; ks < 8; ++ks) {
    const int k = ks * 32 + quad * 8;
    short8 a = *(const short8*)&Ap[w * 16 + lm][k];
#pragma unroll
    for (int nt = 0; nt < 4; ++nt) {
      short8 b = *(const short8*)&Bp[nt * 16 + lm][k];
      acc[nt] = __builtin_amdgcn_mfma_f32_16x16x32_bf16(a, b, acc[nt], 0, 0, 0);
    }
  }

  if (!vmode) {
    // D[t][e]: row t = t0 + w*16 + quad*4 + r ; col e = e0 + nt*16 + lm
#pragma unroll
    for (int nt = 0; nt < 4; ++nt) {
      const int eg = e0 + nt * 16 + lm;   // 0..511
      const float bq = b_qkv[eg];
      __hip_bfloat16* dst = (et < 4) ? Qb : Kb;
      const int eloc = (et < 4) ? eg : (eg - 256);
#pragma unroll
      for (int r = 0; r < 4; ++r) {
        const int t = t0 + w * 16 + quad * 4 + r;
        dst[((size_t)bc * TT + t) * DM + eloc] =
            __float2bfloat16(acc[nt][r] + bq);
      }
    }
  } else {
    // D[e][t]: row e = (e0-512) + w*16 + quad*4 + r ; col t = t0 + nt*16 + lm
#pragma unroll
    for (int r = 0; r < 4; ++r) {
      const int eloc = (e0 - 512) + w * 16 + quad * 4 + r;
      const float bq = b_qkv[512 + eloc];
#pragma unroll
      for (int nt = 0; nt < 4; ++nt) {
        const int t = t0 + nt * 16 + lm;
        Vtb[((size_t)bc * DM + eloc) * TT + t] =
            __float2bfloat16(acc[nt][r] + bq);
      }
    }
  }
}

// ---------------------------------------------------------------------------
// Kernel 2: flash attention (Br=64 q rows per block, Kc=32 per iter).
// grid (16 qtiles, 32 bc), 256 threads (4 waves, each owns a 16-row q band).
// mask arrives as int32 (harness converts integer/bool dtypes to int32).
// ---------------------------------------------------------------------------
__global__ __launch_bounds__(256) void attn_kernel(
    const __hip_bfloat16* __restrict__ Qb, const __hip_bfloat16* __restrict__ Kb,
    const __hip_bfloat16* __restrict__ Vtb, const int* __restrict__ mask,
    __hip_bfloat16* __restrict__ Ob)
{
  const int qt = blockIdx.x, bc = blockIdx.y;
  const int q0 = qt * 64;

  __shared__ __attribute__((aligned(16))) __hip_bfloat16 Ks[64][264];  // K tile (also Q staging)
  __shared__ __attribute__((aligned(16))) __hip_bfloat16 Vs[256][40];  // V^T tile [e][j]
  __shared__ __attribute__((aligned(16))) __hip_bfloat16 Ps[64][40];   // P tile  [q][j]
  __shared__ __attribute__((aligned(16))) unsigned int   Ms[64][8];    // mask bytes [q][j], packed

  const int tid = threadIdx.x, w = tid >> 6, l = tid & 63;
  const int quad = l >> 4, lm = l & 15;

  // stage Q tile through Ks region, pull A-fragments into registers
  const __hip_bfloat16* Qg = Qb + ((size_t)bc * TT + q0) * DM;
  for (int i = 0; i < 8; ++i) {
    const int idx = tid + i * 256, row = idx >> 5, c8 = idx & 31;
    *(uint4*)&Ks[row][c8 * 8] = *(const uint4*)&Qg[(size_t)row * DM + c8 * 8];
  }
  __syncthreads();
  short8 qf[8];
#pragma unroll
  for (int ks = 0; ks < 8; ++ks)
    qf[ks] = *(const short8*)&Ks[w * 16 + lm][ks * 32 + quad * 8];

  f32x4 Oa[16] = {};
  float mrun[4] = {-1e30f, -1e30f, -1e30f, -1e30f};
  float lrun[4] = {0.f, 0.f, 0.f, 0.f};

  for (int j = 0; j < 32; ++j) {
    const int k0 = j * 32;
    __syncthreads();   // previous iter done with Ks/Vs/Ms (also covers qf reads)

    // stage K tile (32 rows x 256)
    const __hip_bfloat16* Kg = Kb + ((size_t)bc * TT + k0) * DM;
    for (int i = 0; i < 4; ++i) {
      const int idx = tid + i * 256, row = idx >> 5, c8 = idx & 31;
      *(uint4*)&Ks[row][c8 * 8] = *(const uint4*)&Kg[(size_t)row * DM + c8 * 8];
    }
    // stage V^T tile (256 rows x 32 cols)
    const __hip_bfloat16* Vg = Vtb + (size_t)bc * DM * TT + k0;
    for (int i = 0; i < 8; ++i) {
      const int idx = tid + i * 256, row = idx >> 3, c4 = idx & 7;
      *(uint2*)&Vs[row][c4 * 4] = *(const uint2*)&Vg[(size_t)row * TT + c4 * 4];
    }
    // stage mask tile (64 rows x 32 int32) -> packed bytes in LDS
    for (int i = 0; i < 2; ++i) {
      const int idx = tid + i * 256;         // 0..511 int4 chunks
      const int row = idx >> 3, c4 = idx & 7;
      const int4 mi = *(const int4*)(mask +
          ((size_t)bc * TT + q0 + row) * TT + k0 + c4 * 4);
      const unsigned packed = (unsigned)(mi.x != 0)       |
                              ((unsigned)(mi.y != 0) << 8)  |
                              ((unsigned)(mi.z != 0) << 16) |
                              ((unsigned)(mi.w != 0) << 24);
      Ms[row][c4] = packed;
    }
    __syncthreads();

    // S = Q K^T, 16x32 per wave
    f32x4 Sa[2] = {};
    for (int ks = 0; ks < 8; ++ks) {
#pragma unroll
      for (int nt = 0; nt < 2; ++nt) {
        short8 b = *(const short8*)&Ks[nt * 16 + lm][ks * 32 + quad * 8];
        Sa[nt] = __builtin_amdgcn_mfma_f32_16x16x32_bf16(qf[ks], b, Sa[nt], 0, 0, 0);
      }
    }

    // mask + scale
    float sv[2][4];
#pragma unroll
    for (int nt = 0; nt < 2; ++nt)
#pragma unroll
      for (int r = 0; r < 4; ++r) {
        const int qr = w * 16 + quad * 4 + r;
        const unsigned char mb =
            ((const unsigned char*)&Ms[qr][0])[nt * 16 + lm];
        sv[nt][r] = mb ? -1e30f : Sa[nt][r] * 0.0625f;
      }

    // online softmax: row max over 16 lanes of the quad group
    float mnew[4], alpha[4];
#pragma unroll
    for (int r = 0; r < 4; ++r) {
      float mx = fmaxf(sv[0][r], sv[1][r]);
      for (int off = 1; off < 16; off <<= 1)
        mx = fmaxf(mx, __shfl_xor(mx, off, 64));
      mnew[r] = fmaxf(mrun[r], mx);
      alpha[r] = __expf(mrun[r] - mnew[r]);
      mrun[r] = mnew[r];
    }
#pragma unroll
    for (int r = 0; r < 4; ++r) {
      float rs = 0.f;
#pragma unroll
      for (int nt = 0; nt < 2; ++nt) {
        const float p = __expf(sv[nt][r] - mnew[r]);
        rs += p;
        Ps[w * 16 + quad * 4 + r][nt * 16 + lm] = __float2bfloat16(p);
      }
      for (int off = 1; off < 16; off <<= 1) rs += __shfl_xor(rs, off, 64);
      lrun[r] = alpha[r] * lrun[r] + rs;
    }

    // O = O*alpha + P V   (P via LDS: per-wave band, in-order DS, no barrier)
    short8 pf = *(const short8*)&Ps[w * 16 + lm][quad * 8];
#pragma unroll
    for (int ct = 0; ct < 16; ++ct) {
      f32x4 o = Oa[ct];
#pragma unroll
      for (int r = 0; r < 4; ++r) o[r] *= alpha[r];
      short8 b = *(const short8*)&Vs[ct * 16 + lm][quad * 8];
      Oa[ct] = __builtin_amdgcn_mfma_f32_16x16x32_bf16(pf, b, o, 0, 0, 0);
    }
  }

  // normalize + write O (bf16, (t,e)-major for out-proj A operand)
  float inv[4];
#pragma unroll
  for (int r = 0; r < 4; ++r) inv[r] = 1.0f / lrun[r];
  __hip_bfloat16* Og = Ob + ((size_t)bc * TT + q0) * DM;
#pragma unroll
  for (int ct = 0; ct < 16; ++ct)
#pragma unroll
    for (int r = 0; r < 4; ++r) {
      const int t = w * 16 + quad * 4 + r;
      Og[(size_t)t * DM + ct * 16 + lm] = __float2bfloat16(Oa[ct][r] * inv[r]);
    }
}

// ---------------------------------------------------------------------------
// Kernel 3: output projection. y[t][f] = sum_e O[t][e] w_out[f][e] + b_out[f]
// grid (4 ftiles, 16 ttiles, 32 bc), 256 threads.
// ---------------------------------------------------------------------------
__global__ __launch_bounds__(256) void proj_kernel(
    const __hip_bfloat16* __restrict__ Ob, const float* __restrict__ w_out,
    const float* __restrict__ b_out, float* __restrict__ out)
{
  const int ft = blockIdx.x, tt = blockIdx.y, bc = blockIdx.z;
  const int f0 = ft * 64, t0 = tt * 64;

  __shared__ __attribute__((aligned(16))) __hip_bfloat16 As[64][264];
  __shared__ __attribute__((aligned(16))) __hip_bfloat16 Bs[64][264];

  const int tid = threadIdx.x;
  const __hip_bfloat16* Og = Ob + ((size_t)bc * TT + t0) * DM;
  for (int i = 0; i < 8; ++i) {
    const int idx = tid + i * 256, row = idx >> 5, c8 = idx & 31;
    *(uint4*)&As[row][c8 * 8] = *(const uint4*)&Og[(size_t)row * DM + c8 * 8];
  }
  {
    const float4* wv = (const float4*)(w_out + (size_t)f0 * DM);
    for (int i = 0; i < 16; ++i) {
      const int idx = tid + i * 256, row = idx >> 6, c4 = idx & 63;
      float4 f = wv[row * 64 + c4];
      Bs[row][c4 * 4 + 0] = __float2bfloat16(f.x);
      Bs[row][c4 * 4 + 1] = __float2bfloat16(f.y);
      Bs[row][c4 * 4 + 2] = __float2bfloat16(f.z);
      Bs[row][c4 * 4 + 3] = __float2bfloat16(f.w);
    }
  }
  __syncthreads();

  const int w = tid >> 6, l = tid & 63, quad = l >> 4, lm = l & 15;
  f32x4 acc[4] = {};
  for (int ks = 0; ks < 8; ++ks) {
    const int k = ks * 32 + quad * 8;
    short8 a = *(const short8*)&As[w * 16 + lm][k];
#pragma unroll
    for (int nt = 0; nt < 4; ++nt) {
      short8 b = *(const short8*)&Bs[nt * 16 + lm][k];
      acc[nt] = __builtin_amdgcn_mfma_f32_16x16x32_bf16(a, b, acc[nt], 0, 0, 0);
    }
  }
#pragma unroll
  for (int nt = 0; nt < 4; ++nt) {
    const int f = f0 + nt * 16 + lm;
    const float bo = b_out[f];
#pragma unroll
    for (int r = 0; r < 4; ++r) {
      const int t = t0 + w * 16 + quad * 4 + r;
      out[((size_t)bc * TT + t) * DM + f] = acc[nt][r] + bo;
    }
  }
}

// ---------------------------------------------------------------------------
extern "C" void kernel_launch(void* const* d_in, const int* in_sizes, int n_in,
                              void* d_out, int out_size, void* d_ws, size_t ws_size,
                              hipStream_t stream) {
  const float* x = (const float*)d_in[0];
  const int* mask = (const int*)d_in[1];  // bool -> int32 per harness contract
  const float* w_qkv = (const float*)d_in[2];
  const float* b_qkv = (const float*)d_in[3];
  const float* w_out = (const float*)d_in[4];
  const float* b_out = (const float*)d_in[5];
  float* out = (float*)d_out;

  const size_t N = (size_t)BCN * TT * DM;            // 8388608 elems
  __hip_bfloat16* Qb  = (__hip_bfloat16*)d_ws;       // 16 MB
  __hip_bfloat16* Kb  = Qb + N;                      // 16 MB
  __hip_bfloat16* Vtb = Kb + N;                      // 16 MB, stored [bc][e][t]
  __hip_bfloat16* Ob  = Vtb + N;                     // 16 MB

  qkv_kernel<<<dim3(12, 16, BCN), dim3(256), 0, stream>>>(x, w_qkv, b_qkv, Qb, Kb, Vtb);
  attn_kernel<<<dim3(16, BCN), dim3(256), 0, stream>>>(Qb, Kb, Vtb, mask, Ob);
  proj_kernel<<<dim3(4, 16, BCN), dim3(256), 0, stream>>>(Ob, w_out, b_out, out);
}